// Round 9
// baseline (589.331 us; speedup 1.0000x reference)
//
#include <hip/hip_runtime.h>

// Izhikevich scan, R8: two-pass checkpoint/replay; pass1 = single-wave deep
// register-ring pipeline (NO LDS, NO barriers, NO multi-wave coordination).
//
// History: izh time invariant ~243-288us across R1/R3/R4/R5 single-kernel
// variants -- the serial core was input-staging/latency-bound, stores were
// cosmetic. R6 split the work: pass2 (5120 replay waves, deep store TLP) is
// near-HBM-roofline; pass1 (single-wave core) remained ~190us. R7/R7b
// multi-wave-staged pass1 never ran (3x broker/container infra failures on
// 2 different barrier implementations; R6, 95% structurally identical,
// passed) -- so R8 gets the same staging bandwidth WITHOUT any inter-wave
// machinery: a 25-deep per-lane register ring. Consume ri[j], reload it with
// the input 25 steps ahead => reuse distance ~1100cyc > ~900cyc HBM latency,
// ~25 outstanding loads (6.4KB/wave in flight ~ 7 B/cyc) => 512KB/block
// staged hidden under ~90k cyc of dependency-chain compute. Nothing in
// pass1 can deadlock: straight-line unrolled bodies, wave-uniform loops.
//
// Pass 1 (256 blocks x 64 threads): recurrence + (v,u) checkpoint to d_ws
//   every 100 steps. Loads only (2 scalar checkpoint stores per 100 steps).
// Pass 2 (20x256 blocks x 64 threads, BYTE-IDENTICAL to R6-verified): each
//   wave replays a 100-step segment from its checkpoint, writes s/v/u.
//
// NUMERICS: exact numpy op order, fp contract off; checkpoint replay is
// bit-identical to a continuous scan.

#define NSTEPS 2000
#define NNEUR  512
#define BATCH  32
#define INPLANE 1024000u                       // NSTEPS*NNEUR per batch
#define PLANE  32768000u                       // BATCH*NSTEPS*NNEUR per out plane
#define CHUNK  100                             // steps per checkpoint segment
#define NCHUNK (NSTEPS / CHUNK)                // 20
#define NCHAIN 16384u                          // BATCH*NNEUR
#define PF     25                              // pass1 register-ring depth
#define WIN    10                              // pass2 inner window (steps)

__device__ __forceinline__ void izh_step(float i_t, float& v, float& u, float& s) {
#pragma clang fp contract(off)
    float t1 = 0.04f * v;
    t1 = t1 * v;
    float t2 = 5.0f * v;
    float acc = t1 + t2;
    acc = acc + 140.0f;
    acc = acc - u;
    acc = acc + i_t;
    float dv = acc * 0.5f;
    float t4 = 0.2f * v;
    t4 = t4 - u;
    t4 = 0.02f * t4;
    float du = t4 * 0.5f;
    v = v + dv;
    u = u + du;
    bool sp = (v >= 30.0f);
    s = sp ? 1.0f : 0.0f;
    v = sp ? -65.0f : v;
    u = sp ? (u + 8.0f) : u;
}

// ---------------- pass 1: register-ring recurrence, checkpoints only -------
__global__ __launch_bounds__(64, 1) void izh_pass1(const float* __restrict__ in,
                                                   float* __restrict__ ckV,
                                                   float* __restrict__ ckU) {
    const int lane = threadIdx.x;
    const unsigned gid = blockIdx.x * 64u + (unsigned)lane;   // chain id
    const unsigned b   = gid >> 9;
    const unsigned n   = gid & (NNEUR - 1);
    const float* ip = in + (size_t)b * INPLANE + n;

    // prologue: fill ring with steps 0..PF-1
    float ri[PF];
#pragma unroll
    for (int j = 0; j < PF; ++j) ri[j] = ip[(size_t)j * NNEUR];

    float v = -65.0f, u = -13.0f;              // C, B*C exactly

    // segments 0..18: checkpoint, then 100 steps with full ring reload.
    // Group g consumes steps s*100+g*25..+24; the reload of ri[j] is the
    // input for step (t+PF), consumed one group later (reuse dist 25 steps).
    for (int s = 0; s < NCHUNK - 1; ++s) {
        ckV[(unsigned)s * NCHAIN + gid] = v;   // state entering step 100*s
        ckU[(unsigned)s * NCHAIN + gid] = u;
        const float* lp = ip + (size_t)((unsigned)s * CHUNK + PF) * NNEUR;
#pragma unroll
        for (int g = 0; g < CHUNK / PF; ++g) {
#pragma unroll
            for (int j = 0; j < PF; ++j) {
                float sp;
                izh_step(ri[j], v, u, sp);
                ri[j] = lp[(size_t)(g * PF + j) * NNEUR];
            }
        }
    }
    // segment 19: groups 0..2 reload (steps 1925..1999), group 3 consume-only
    ckV[(unsigned)(NCHUNK - 1) * NCHAIN + gid] = v;
    ckU[(unsigned)(NCHUNK - 1) * NCHAIN + gid] = u;
    const float* lp = ip + (size_t)((unsigned)(NCHUNK - 1) * CHUNK + PF) * NNEUR;
#pragma unroll
    for (int g = 0; g < CHUNK / PF - 1; ++g) {
#pragma unroll
        for (int j = 0; j < PF; ++j) {
            float sp;
            izh_step(ri[j], v, u, sp);
            ri[j] = lp[(size_t)(g * PF + j) * NNEUR];
        }
    }
#pragma unroll
    for (int j = 0; j < PF; ++j) {
        float sp;
        izh_step(ri[j], v, u, sp);
    }
}

// ---------------- pass 2: segment replay + all output stores ---------------
// (byte-identical to R6, hardware-verified)
__global__ __launch_bounds__(64, 4) void izh_pass2(const float* __restrict__ in,
                                                   float* __restrict__ out,
                                                   const float* __restrict__ ckV,
                                                   const float* __restrict__ ckU) {
    const int lane = threadIdx.x;
    const unsigned sp  = (unsigned)blockIdx.x & 255u;    // chain-group
    const unsigned seg = (unsigned)blockIdx.x >> 8;      // time segment 0..19
    const unsigned gid = sp * 64u + (unsigned)lane;
    const unsigned b   = gid >> 9;
    const unsigned n   = gid & (NNEUR - 1);

    float v = ckV[seg * NCHAIN + gid];
    float u = ckU[seg * NCHAIN + gid];

    const size_t base = (size_t)b * INPLANE + (size_t)seg * CHUNK * NNEUR + n;
    const float* ip = in + base;
    float* oS = out;
    float* oV = out + (size_t)PLANE;
    float* oU = out + 2 * (size_t)PLANE;
    size_t off = base;

    float ra[WIN], rb[WIN];
#pragma unroll
    for (int j = 0; j < WIN; ++j) ra[j] = ip[(size_t)j * NNEUR];

    for (int w = 0; w < CHUNK / WIN; w += 2) {
        // prefetch window w+1 while computing window w
#pragma unroll
        for (int j = 0; j < WIN; ++j) rb[j] = ip[(size_t)((w + 1) * WIN + j) * NNEUR];
        {
            float sB[WIN], vB[WIN], uB[WIN];
#pragma unroll
            for (int j = 0; j < WIN; ++j) { izh_step(ra[j], v, u, sB[j]); vB[j] = v; uB[j] = u; }
#pragma unroll
            for (int j = 0; j < WIN; ++j) {
                oS[off + (size_t)j * NNEUR] = sB[j];
                oV[off + (size_t)j * NNEUR] = vB[j];
                oU[off + (size_t)j * NNEUR] = uB[j];
            }
            off += (size_t)WIN * NNEUR;
        }
        if (w + 2 < CHUNK / WIN) {
#pragma unroll
            for (int j = 0; j < WIN; ++j) ra[j] = ip[(size_t)((w + 2) * WIN + j) * NNEUR];
        }
        {
            float sB[WIN], vB[WIN], uB[WIN];
#pragma unroll
            for (int j = 0; j < WIN; ++j) { izh_step(rb[j], v, u, sB[j]); vB[j] = v; uB[j] = u; }
#pragma unroll
            for (int j = 0; j < WIN; ++j) {
                oS[off + (size_t)j * NNEUR] = sB[j];
                oV[off + (size_t)j * NNEUR] = vB[j];
                oU[off + (size_t)j * NNEUR] = uB[j];
            }
            off += (size_t)WIN * NNEUR;
        }
    }
}

extern "C" void kernel_launch(void* const* d_in, const int* in_sizes, int n_in,
                              void* d_out, int out_size, void* d_ws, size_t ws_size,
                              hipStream_t stream) {
    const float* in = (const float*)d_in[0];
    float* out = (float*)d_out;
    float* ckV = (float*)d_ws;                         // 20*16384 floats
    float* ckU = ckV + (size_t)NCHUNK * NCHAIN;        // +1.31 MB (2.62 MB total)
    izh_pass1<<<256, 64, 0, stream>>>(in, ckV, ckU);
    izh_pass2<<<NCHUNK * 256, 64, 0, stream>>>(in, out, ckV, ckU);
}